// Round 5
// baseline (1191.451 us; speedup 1.0000x reference)
//
#include <hip/hip_runtime.h>
#include <hip/hip_bf16.h>

// GQA fused block, MI355X. B=2,S=2048,E=2048,H=16,G=2,D=128.
// x->bf16 ; W^T bf16 ; fused QKV GEMM (dbuf global_load_lds) -> C f32 ;
// rmsnorm q,k -> bf16 ; V^T ; barrier-free swapped-operand flash attention ;
// out GEMM (dbuf).

typedef short  bf16x8 __attribute__((ext_vector_type(8)));
typedef float  f32x4  __attribute__((ext_vector_type(4)));
typedef unsigned short u16x8 __attribute__((ext_vector_type(8)));

static __device__ __forceinline__ unsigned short f2bf(float f) {
    __hip_bfloat16 h = __float2bfloat16(f);   // RNE
    return *reinterpret_cast<unsigned short*>(&h);
}

static __device__ __forceinline__ void load_lds16(const void* g, void* l) {
    __builtin_amdgcn_global_load_lds(
        (const __attribute__((address_space(1))) void*)g,
        (__attribute__((address_space(3))) void*)l, 16, 0, 0);
}

// ---------------- x f32 -> bf16 ------------------------------------------------------
__global__ __launch_bounds__(256)
void cvt_bf16_k(const float* __restrict__ X, unsigned short* __restrict__ Y, int n8) {
    int i = blockIdx.x * 256 + threadIdx.x;
    if (i >= n8) return;
    float4 a = *(const float4*)(X + (size_t)i * 8);
    float4 b = *(const float4*)(X + (size_t)i * 8 + 4);
    u16x8 o{f2bf(a.x), f2bf(a.y), f2bf(a.z), f2bf(a.w),
            f2bf(b.x), f2bf(b.y), f2bf(b.z), f2bf(b.w)};
    *(u16x8*)(Y + (size_t)i * 8) = o;
}

// ---------------- strided transpose + cvt: W[k][n] -> Wt[n][k] -----------------------
__global__ __launch_bounds__(256)
void transpose_cvt2(const float* __restrict__ W, unsigned short* __restrict__ Wt,
                    int in_stride, int K) {
    __shared__ float t[32][33];
    int n0 = blockIdx.x * 32, k0 = blockIdx.y * 32;
    int tx = threadIdx.x & 31, ty = threadIdx.x >> 5;     // 32 x 8
#pragma unroll
    for (int i = 0; i < 32; i += 8)
        t[ty + i][tx] = W[(size_t)(k0 + ty + i) * in_stride + n0 + tx];
    __syncthreads();
#pragma unroll
    for (int i = 0; i < 32; i += 8)
        Wt[(size_t)(n0 + ty + i) * K + k0 + tx] = f2bf(t[tx][ty + i]);
}

// ---------------- bias concat --------------------------------------------------------
__global__ __launch_bounds__(256)
void concat_bias(const float* __restrict__ bq, const float* __restrict__ bk,
                 const float* __restrict__ bv, float* __restrict__ o) {
    int i = blockIdx.x * 256 + threadIdx.x;
    if (i >= 2560) return;
    o[i] = (i < 2048) ? bq[i] : (i < 2304 ? bk[i - 2048] : bv[i - 2304]);
}

// ---------------- GEMM (dbuf, 1 barrier/K-step): C f32 = A bf16 @ Bt^T + bias --------
__global__ __launch_bounds__(256)
void gemm_lds(const unsigned short* __restrict__ A, const unsigned short* __restrict__ Bt,
              const float* __restrict__ bias, float* __restrict__ Cout,
              int M, int N, int K) {
    __shared__ unsigned short Al[2][128 * 32];
    __shared__ unsigned short Bl[2][128 * 32];
    // bijective XCD swizzle (all launches have nwg % 8 == 0)
    int nwg = gridDim.x * gridDim.y;
    int bid = blockIdx.y * gridDim.x + blockIdx.x;
    int swz = (bid & 7) * (nwg >> 3) + (bid >> 3);
    int m0 = (swz / gridDim.x) * 128, n0 = (swz % gridDim.x) * 128;

    int tid = threadIdx.x, lane = tid & 63, w = tid >> 6;
    int wr = w >> 1, wc = w & 1, lg = lane >> 4, lr = lane & 15;

    f32x4 acc[4][4];
#pragma unroll
    for (int i = 0; i < 4; i++)
#pragma unroll
        for (int j = 0; j < 4; j++) acc[i][j] = f32x4{0.f, 0.f, 0.f, 0.f};

    int srow = w * 16 + (lane >> 2);
    int scol = (lane & 3) * 8;
    const unsigned short* ga = A  + (size_t)(m0 + srow) * K + scol;
    const unsigned short* gb = Bt + (size_t)(n0 + srow) * K + scol;

    auto stage = [&](int buf, int k0) {
        unsigned short* la = &Al[buf][w * 512];
        unsigned short* lb = &Bl[buf][w * 512];
        load_lds16(ga + k0,                  la);
        load_lds16(ga + (size_t)64 * K + k0, la + 2048);
        load_lds16(gb + k0,                  lb);
        load_lds16(gb + (size_t)64 * K + k0, lb + 2048);
    };
    stage(0, 0);
    __syncthreads();

    for (int k0 = 0; k0 < K; k0 += 32) {
        int cur = (k0 >> 5) & 1;
        if (k0 + 32 < K) stage(cur ^ 1, k0 + 32);
        bf16x8 af[4], bfv[4];
#pragma unroll
        for (int mi = 0; mi < 4; mi++)
            af[mi] = *(const bf16x8*)&Al[cur][(wr * 64 + mi * 16 + lr) * 32 + 8 * lg];
#pragma unroll
        for (int ni = 0; ni < 4; ni++)
            bfv[ni] = *(const bf16x8*)&Bl[cur][(wc * 64 + ni * 16 + lr) * 32 + 8 * lg];
#pragma unroll
        for (int mi = 0; mi < 4; mi++)
#pragma unroll
            for (int ni = 0; ni < 4; ni++)
                acc[mi][ni] = __builtin_amdgcn_mfma_f32_16x16x32_bf16(af[mi], bfv[ni], acc[mi][ni], 0, 0, 0);
        __syncthreads();
    }

#pragma unroll
    for (int mi = 0; mi < 4; mi++)
#pragma unroll
        for (int ni = 0; ni < 4; ni++) {
            int col = n0 + wc * 64 + ni * 16 + lr;
            float bv = bias[col];
#pragma unroll
            for (int r = 0; r < 4; r++) {
                int row = m0 + wr * 64 + mi * 16 + 4 * lg + r;
                Cout[(size_t)row * N + col] = acc[mi][ni][r] + bv;
            }
        }
}

// ---------------- RMSNorm 128-chunks from strided f32 -> bf16 ------------------------
__global__ __launch_bounds__(256)
void rmsnorm_cvt2(const float* __restrict__ C, const float* __restrict__ gamma,
                  unsigned short* __restrict__ Y, int in_stride, int in_off,
                  int cl, int total) {
    int wave = blockIdx.x * 4 + (threadIdx.x >> 6);
    int lane = threadIdx.x & 63;
    if (wave >= total) return;
    int token = wave >> cl, c = wave & ((1 << cl) - 1);
    const float* in = C + (size_t)token * in_stride + in_off + c * 128;
    float2 v = *(const float2*)(in + lane * 2);
    float ss = v.x * v.x + v.y * v.y;
#pragma unroll
    for (int m = 1; m < 64; m <<= 1) ss += __shfl_xor(ss, m);
    float inv = rsqrtf(ss * (1.0f / 128.0f) + 1e-8f);
    float2 gv = *(const float2*)(gamma + lane * 2);
    unsigned short o0 = f2bf(v.x * inv * gv.x);
    unsigned short o1 = f2bf(v.y * inv * gv.y);
    ((unsigned int*)Y)[((size_t)token * (1 << cl) + c) * 64 + lane] =
        (unsigned)o0 | ((unsigned)o1 << 16);
}

// ---------------- causal GQA flash attention, barrier-free ---------------------------
// grid 512 blocks, 256 thr. Swapped-operand MFMA: S^T = mfma(K,Q), O^T = mfma(V^T,P^T).
// Each lane owns q-row q=lr -> scalar online softmax. K/V frags straight from L1/L2.
// Block processes paired q-tiles {p, 31-p} in ONE merged kv loop (uniform 32 iters).
__global__ __launch_bounds__(256, 2)
void attn_kernel(const unsigned short* __restrict__ Qb,   // [4096][2048] bf16 normed
                 const unsigned short* __restrict__ Kb,   // [4096][256]  bf16 normed
                 const unsigned short* __restrict__ Vt,   // [512][4096]  bf16 V^T
                 unsigned short* __restrict__ Ctx) {      // [4096][2048] bf16
    const int S = 2048;
    // XCD-aware decode: same (b,g) -> same XCD pair (K/V L2 locality)
    int bid = blockIdx.x;
    int xcd = bid & 7, ii = bid >> 3;
    int g2 = xcd >> 1;
    int local = (xcd & 1) * 64 + ii;          // 0..127
    int pair = local & 15, hl = local >> 4;   // hl 0..7
    int b = g2 >> 1, g = g2 & 1, h = g * 8 + hl;

    int tid = threadIdx.x, lane = tid & 63, w = tid >> 6;
    int lg = lane >> 4, lr = lane & 15;
    size_t tok0 = (size_t)b * S;

    int qtA = pair, qtB = 31 - pair;
    int qA0 = qtA * 64 + w * 16, qB0 = qtB * 64 + w * 16;   // wave's 16-row base

    __shared__ unsigned short Pl[4][2][16][72];   // per-wave P^T [q=lr][kv], 144B rows
    __shared__ unsigned short Ob[4][16][136];     // per-wave O transpose buffer

    const float cexp = 0.08838834764831845f * 1.4426950408889634f; // 1/sqrt(128)*log2e

    bf16x8 qfA[4], qfB[4];
#pragma unroll
    for (int ks = 0; ks < 4; ks++) {
        qfA[ks] = *(const bf16x8*)(Qb + (tok0 + qA0 + lr) * 2048 + h * 128 + ks * 32 + 8 * lg);
        qfB[ks] = *(const bf16x8*)(Qb + (tok0 + qB0 + lr) * 2048 + h * 128 + ks * 32 + 8 * lg);
    }

    f32x4 oA[8], oB[8];
#pragma unroll
    for (int t = 0; t < 8; t++) { oA[t] = f32x4{0.f,0.f,0.f,0.f}; oB[t] = f32x4{0.f,0.f,0.f,0.f}; }
    float mA = -1e30f, lA = 0.f, mB = -1e30f, lB = 0.f;

    const unsigned short* kb0 = Kb + tok0 * 256 + g * 128 + 8 * lg;
    const unsigned short* vb0 = Vt + ((size_t)(g * 128 + lr)) * 4096 + tok0 + 8 * lg;

    for (int kvt = 0; kvt <= qtB; kvt++) {
        int kv0 = kvt * 64;
        bool doA = (kvt <= qtA);

        // ---- S^T tiles = mfma(K, Q); K frags shared by both halves
        f32x4 sA[4], sB[4];
#pragma unroll
        for (int c = 0; c < 4; c++) { sA[c] = f32x4{0.f,0.f,0.f,0.f}; sB[c] = f32x4{0.f,0.f,0.f,0.f}; }
#pragma unroll
        for (int c = 0; c < 4; c++) {
            bf16x8 kf[4];
#pragma unroll
            for (int ks = 0; ks < 4; ks++)
                kf[ks] = *(const bf16x8*)(kb0 + (size_t)(kv0 + c * 16 + lr) * 256 + ks * 32);
#pragma unroll
            for (int ks = 0; ks < 4; ks++) {
                sB[c] = __builtin_amdgcn_mfma_f32_16x16x32_bf16(kf[ks], qfB[ks], sB[c], 0, 0, 0);
                if (doA)
                    sA[c] = __builtin_amdgcn_mfma_f32_16x16x32_bf16(kf[ks], qfA[ks], sA[c], 0, 0, 0);
            }
        }

        // ---- per-lane scalar online softmax; write P^T packed u32 into per-wave LDS
        auto softmax_half = [&](f32x4 (&sacc)[4], float& mX, float& lX, f32x4 (&oX)[8],
                                int qX0, bool diagtile, int pslot) {
            float pv[4][4];
            float pm = -1e30f;
#pragma unroll
            for (int c = 0; c < 4; c++)
#pragma unroll
                for (int r = 0; r < 4; r++) {
                    float s = sacc[c][r] * cexp;
                    if (diagtile && (kv0 + 16 * c + 4 * lg + r > qX0 + lr)) s = -1e30f;
                    pv[c][r] = s;
                    pm = fmaxf(pm, s);
                }
            pm = fmaxf(pm, __shfl_xor(pm, 16));
            pm = fmaxf(pm, __shfl_xor(pm, 32));
            if (!__all(pm <= mX + 8.0f)) {          // T13 defer-max (P bounded by 2^8)
                float mn = fmaxf(mX, pm);
                float al = __builtin_exp2f(mX - mn);
                mX = mn;
                lX *= al;
#pragma unroll
                for (int t = 0; t < 8; t++)
#pragma unroll
                    for (int r = 0; r < 4; r++) oX[t][r] *= al;
            }
            float ts = 0.f;
#pragma unroll
            for (int c = 0; c < 4; c++)
#pragma unroll
                for (int r = 0; r < 4; r++) {
                    float e = __builtin_exp2f(pv[c][r] - mX);
                    pv[c][r] = e;
                    ts += e;
                }
            ts += __shfl_xor(ts, 16);
            ts += __shfl_xor(ts, 32);
            lX += ts;
#pragma unroll
            for (int c = 0; c < 4; c++)
#pragma unroll
                for (int e = 0; e < 2; e++) {
                    unsigned u = (unsigned)f2bf(pv[c][2 * e]) |
                                 ((unsigned)f2bf(pv[c][2 * e + 1]) << 16);
                    *(unsigned*)&Pl[w][pslot][lr][16 * c + 4 * lg + 2 * e] = u;
                }
        };
        softmax_half(sB, mB, lB, oB, qB0, kvt == qtB, 0);
        if (doA) softmax_half(sA, mA, lA, oA, qA0, kvt == qtA, 1);

        // ---- O^T += mfma(V^T, P^T); V frags shared by both halves
        bf16x8 pB0 = *(const bf16x8*)&Pl[w][0][lr][8 * lg];
        bf16x8 pB1 = *(const bf16x8*)&Pl[w][0][lr][32 + 8 * lg];
        bf16x8 pA0, pA1;
        if (doA) {
            pA0 = *(const bf16x8*)&Pl[w][1][lr][8 * lg];
            pA1 = *(const bf16x8*)&Pl[w][1][lr][32 + 8 * lg];
        }
#pragma unroll
        for (int t = 0; t < 8; t++) {
            bf16x8 v0 = *(const bf16x8*)(vb0 + (size_t)t * 16 * 4096 + kv0);
            bf16x8 v1 = *(const bf16x8*)(vb0 + (size_t)t * 16 * 4096 + kv0 + 32);
            oB[t] = __builtin_amdgcn_mfma_f32_16x16x32_bf16(v0, pB0, oB[t], 0, 0, 0);
            oB[t] = __builtin_amdgcn_mfma_f32_16x16x32_bf16(v1, pB1, oB[t], 0, 0, 0);
            if (doA) {
                oA[t] = __builtin_amdgcn_mfma_f32_16x16x32_bf16(v0, pA0, oA[t], 0, 0, 0);
                oA[t] = __builtin_amdgcn_mfma_f32_16x16x32_bf16(v1, pA1, oA[t], 0, 0, 0);
            }
        }
    }

    // ---- epilogue: O^T -> LDS transpose -> coalesced bf16 stores
    auto epilogue = [&](f32x4 (&oX)[8], float lX, int qX0) {
        float inv = 1.0f / lX;
#pragma unroll
        for (int t = 0; t < 8; t++)
#pragma unroll
            for (int e = 0; e < 2; e++) {
                unsigned u = (unsigned)f2bf(oX[t][2 * e] * inv) |
                             ((unsigned)f2bf(oX[t][2 * e + 1] * inv) << 16);
                *(unsigned*)&Ob[w][lr][16 * t + 4 * lg + 2 * e] = u;
            }
        int orow = lane >> 2, oc = lane & 3;
#pragma unroll
        for (int p = 0; p < 4; p++) {
            bf16x8 vv = *(const bf16x8*)&Ob[w][orow][(oc + 4 * p) * 8];
            *(bf16x8*)(Ctx + (tok0 + qX0 + orow) * 2048 + h * 128 + (oc + 4 * p) * 8) = vv;
        }
    };
    epilogue(oB, lB, qB0);
    epilogue(oA, lA, qA0);
}

// ---------------- launch --------------------------------------------------------------
extern "C" void kernel_launch(void* const* d_in, const int* in_sizes, int n_in,
                              void* d_out, int out_size, void* d_ws, size_t ws_size,
                              hipStream_t stream) {
    const float* x  = (const float*)d_in[0];
    const float* Wq = (const float*)d_in[1];
    const float* bq = (const float*)d_in[2];
    const float* Wk = (const float*)d_in[3];
    const float* bk = (const float*)d_in[4];
    const float* Wv = (const float*)d_in[5];
    const float* bv = (const float*)d_in[6];
    const float* gq = (const float*)d_in[7];
    const float* gk = (const float*)d_in[8];
    const float* Wo = (const float*)d_in[9];
    const float* bo = (const float*)d_in[10];
    float* out = (float*)d_out;

    char* ws = (char*)d_ws;
    size_t off = 0;
    auto alloc = [&](size_t bytes) {
        void* p = ws + off;
        off += (bytes + 255) & ~(size_t)255;
        return p;
    };
    unsigned short* wqkvt = (unsigned short*)alloc((size_t)2560 * 2048 * 2);
    unsigned short* wot   = (unsigned short*)alloc((size_t)2048 * 2048 * 2);
    unsigned short* xb    = (unsigned short*)alloc((size_t)4096 * 2048 * 2);  // reused as ctx
    float*          C     = (float*)alloc((size_t)4096 * 2560 * 4);
    unsigned short* qb_   = (unsigned short*)alloc((size_t)4096 * 2048 * 2);
    unsigned short* kb_   = (unsigned short*)alloc((size_t)4096 * 256 * 2);
    unsigned short* vt    = (unsigned short*)alloc((size_t)512 * 4096 * 2);
    float*          biascat = (float*)alloc((size_t)2560 * 4);
    unsigned short* ctx = xb;   // xb dead after proj GEMM

    // x -> bf16
    cvt_bf16_k<<<4096, 256, 0, stream>>>(x, xb, 1048576);
    // weights -> K-major bf16 (QKV fused)
    transpose_cvt2<<<dim3(64, 64), 256, 0, stream>>>(Wq, wqkvt, 2048, 2048);
    transpose_cvt2<<<dim3(8, 64),  256, 0, stream>>>(Wk, wqkvt + (size_t)2048 * 2048, 256, 2048);
    transpose_cvt2<<<dim3(8, 64),  256, 0, stream>>>(Wv, wqkvt + (size_t)2304 * 2048, 256, 2048);
    transpose_cvt2<<<dim3(64, 64), 256, 0, stream>>>(Wo, wot, 2048, 2048);
    concat_bias<<<10, 256, 0, stream>>>(bq, bk, bv, biascat);

    // fused QKV projection -> C f32 [4096][2560]
    gemm_lds<<<dim3(20, 32), 256, 0, stream>>>(xb, wqkvt, biascat, C, 4096, 2560, 2048);

    // per-head RMSNorm + cvt
    rmsnorm_cvt2<<<16384, 256, 0, stream>>>(C, gq, qb_, 2560, 0,    4, 65536);
    rmsnorm_cvt2<<<2048,  256, 0, stream>>>(C, gk, kb_, 2560, 2048, 1, 8192);
    // V block -> V^T bf16 [512][4096]
    transpose_cvt2<<<dim3(16, 128), 256, 0, stream>>>(C + 2304, vt, 2560, 4096);

    // attention
    attn_kernel<<<512, 256, 0, stream>>>(qb_, kb_, vt, ctx);

    // output projection -> f32 out
    gemm_lds<<<dim3(16, 32), 256, 0, stream>>>(ctx, wot, bo, out, 4096, 2048, 2048);
}

// Round 8
// 327.042 us; speedup vs baseline: 3.6431x; 3.6431x over previous
//
#include <hip/hip_runtime.h>
#include <hip/hip_bf16.h>

// GQA fused block, MI355X. B=2,S=2048,E=2048,H=16,G=2,D=128.
// x->bf16 ; W^T bf16 ; fused QKV GEMM (dbuf global_load_lds) -> C f32 ;
// rmsnorm q,k -> bf16 ; V^T ; flash attention: LDS-staged dbuf K/V,
// swapped-operand MFMA (per-lane scalar softmax) ; out GEMM (dbuf).

typedef short  bf16x8 __attribute__((ext_vector_type(8)));
typedef float  f32x4  __attribute__((ext_vector_type(4)));
typedef unsigned short u16x8 __attribute__((ext_vector_type(8)));
typedef unsigned short u16x4 __attribute__((ext_vector_type(4)));

static __device__ __forceinline__ unsigned short f2bf(float f) {
    __hip_bfloat16 h = __float2bfloat16(f);   // RNE
    return *reinterpret_cast<unsigned short*>(&h);
}

static __device__ __forceinline__ void load_lds16(const void* g, void* l) {
    __builtin_amdgcn_global_load_lds(
        (const __attribute__((address_space(1))) void*)g,
        (__attribute__((address_space(3))) void*)l, 16, 0, 0);
}

// ---------------- x f32 -> bf16 ------------------------------------------------------
__global__ __launch_bounds__(256)
void cvt_bf16_k(const float* __restrict__ X, unsigned short* __restrict__ Y, int n8) {
    int i = blockIdx.x * 256 + threadIdx.x;
    if (i >= n8) return;
    float4 a = *(const float4*)(X + (size_t)i * 8);
    float4 b = *(const float4*)(X + (size_t)i * 8 + 4);
    u16x8 o{f2bf(a.x), f2bf(a.y), f2bf(a.z), f2bf(a.w),
            f2bf(b.x), f2bf(b.y), f2bf(b.z), f2bf(b.w)};
    *(u16x8*)(Y + (size_t)i * 8) = o;
}

// ---------------- strided transpose + cvt: W[k][n] -> Wt[n][k] -----------------------
__global__ __launch_bounds__(256)
void transpose_cvt2(const float* __restrict__ W, unsigned short* __restrict__ Wt,
                    int in_stride, int K) {
    __shared__ float t[32][33];
    int n0 = blockIdx.x * 32, k0 = blockIdx.y * 32;
    int tx = threadIdx.x & 31, ty = threadIdx.x >> 5;     // 32 x 8
#pragma unroll
    for (int i = 0; i < 32; i += 8)
        t[ty + i][tx] = W[(size_t)(k0 + ty + i) * in_stride + n0 + tx];
    __syncthreads();
#pragma unroll
    for (int i = 0; i < 32; i += 8)
        Wt[(size_t)(n0 + ty + i) * K + k0 + tx] = f2bf(t[tx][ty + i]);
}

// ---------------- bias concat --------------------------------------------------------
__global__ __launch_bounds__(256)
void concat_bias(const float* __restrict__ bq, const float* __restrict__ bk,
                 const float* __restrict__ bv, float* __restrict__ o) {
    int i = blockIdx.x * 256 + threadIdx.x;
    if (i >= 2560) return;
    o[i] = (i < 2048) ? bq[i] : (i < 2304 ? bk[i - 2048] : bv[i - 2304]);
}

// ---------------- GEMM (dbuf, 1 barrier/K-step): C f32 = A bf16 @ Bt^T + bias --------
__global__ __launch_bounds__(256)
void gemm_lds(const unsigned short* __restrict__ A, const unsigned short* __restrict__ Bt,
              const float* __restrict__ bias, float* __restrict__ Cout,
              int M, int N, int K) {
    __shared__ unsigned short Al[2][128 * 32];
    __shared__ unsigned short Bl[2][128 * 32];
    // bijective XCD swizzle (all launches have nwg % 8 == 0)
    int nwg = gridDim.x * gridDim.y;
    int bid = blockIdx.y * gridDim.x + blockIdx.x;
    int swz = (bid & 7) * (nwg >> 3) + (bid >> 3);
    int m0 = (swz / gridDim.x) * 128, n0 = (swz % gridDim.x) * 128;

    int tid = threadIdx.x, lane = tid & 63, w = tid >> 6;
    int wr = w >> 1, wc = w & 1, lg = lane >> 4, lr = lane & 15;

    f32x4 acc[4][4];
#pragma unroll
    for (int i = 0; i < 4; i++)
#pragma unroll
        for (int j = 0; j < 4; j++) acc[i][j] = f32x4{0.f, 0.f, 0.f, 0.f};

    int srow = w * 16 + (lane >> 2);
    int scol = (lane & 3) * 8;
    const unsigned short* ga = A  + (size_t)(m0 + srow) * K + scol;
    const unsigned short* gb = Bt + (size_t)(n0 + srow) * K + scol;

    auto stage = [&](int buf, int k0) {
        unsigned short* la = &Al[buf][w * 512];
        unsigned short* lb = &Bl[buf][w * 512];
        load_lds16(ga + k0,                  la);
        load_lds16(ga + (size_t)64 * K + k0, la + 2048);
        load_lds16(gb + k0,                  lb);
        load_lds16(gb + (size_t)64 * K + k0, lb + 2048);
    };
    stage(0, 0);
    __syncthreads();

    for (int k0 = 0; k0 < K; k0 += 32) {
        int cur = (k0 >> 5) & 1;
        if (k0 + 32 < K) stage(cur ^ 1, k0 + 32);
        bf16x8 af[4], bfv[4];
#pragma unroll
        for (int mi = 0; mi < 4; mi++)
            af[mi] = *(const bf16x8*)&Al[cur][(wr * 64 + mi * 16 + lr) * 32 + 8 * lg];
#pragma unroll
        for (int ni = 0; ni < 4; ni++)
            bfv[ni] = *(const bf16x8*)&Bl[cur][(wc * 64 + ni * 16 + lr) * 32 + 8 * lg];
#pragma unroll
        for (int mi = 0; mi < 4; mi++)
#pragma unroll
            for (int ni = 0; ni < 4; ni++)
                acc[mi][ni] = __builtin_amdgcn_mfma_f32_16x16x32_bf16(af[mi], bfv[ni], acc[mi][ni], 0, 0, 0);
        __syncthreads();
    }

#pragma unroll
    for (int mi = 0; mi < 4; mi++)
#pragma unroll
        for (int ni = 0; ni < 4; ni++) {
            int col = n0 + wc * 64 + ni * 16 + lr;
            float bv = bias[col];
#pragma unroll
            for (int r = 0; r < 4; r++) {
                int row = m0 + wr * 64 + mi * 16 + 4 * lg + r;
                Cout[(size_t)row * N + col] = acc[mi][ni][r] + bv;
            }
        }
}

// ---------------- RMSNorm 128-chunks from strided f32 -> bf16 ------------------------
__global__ __launch_bounds__(256)
void rmsnorm_cvt2(const float* __restrict__ C, const float* __restrict__ gamma,
                  unsigned short* __restrict__ Y, int in_stride, int in_off,
                  int cl, int total) {
    int wave = blockIdx.x * 4 + (threadIdx.x >> 6);
    int lane = threadIdx.x & 63;
    if (wave >= total) return;
    int token = wave >> cl, c = wave & ((1 << cl) - 1);
    const float* in = C + (size_t)token * in_stride + in_off + c * 128;
    float2 v = *(const float2*)(in + lane * 2);
    float ss = v.x * v.x + v.y * v.y;
#pragma unroll
    for (int m = 1; m < 64; m <<= 1) ss += __shfl_xor(ss, m);
    float inv = rsqrtf(ss * (1.0f / 128.0f) + 1e-8f);
    float2 gv = *(const float2*)(gamma + lane * 2);
    unsigned short o0 = f2bf(v.x * inv * gv.x);
    unsigned short o1 = f2bf(v.y * inv * gv.y);
    ((unsigned int*)Y)[((size_t)token * (1 << cl) + c) * 64 + lane] =
        (unsigned)o0 | ((unsigned)o1 << 16);
}

// ---------------- causal GQA flash attention -----------------------------------------
// grid (16,16,2), 256 thr. LDS-staged dbuf K/V (global_load_lds, both-sides XOR
// swizzle). Swapped-operand MFMA: S^T = mfma(K,Q) -> lane owns q-row q0+lr ->
// per-lane scalar online softmax (2 shfls per reduce). O^T = mfma(V^T, P^T).
// Paired q-tiles {p, 31-p} sequentially -> uniform 33 tiles/block.
__global__ __launch_bounds__(256)
void attn_kernel(const unsigned short* __restrict__ Qb,   // [4096][2048] bf16 normed
                 const unsigned short* __restrict__ Kb,   // [4096][256]  bf16 normed
                 const unsigned short* __restrict__ Vt,   // [512][4096]  bf16 V^T
                 unsigned short* __restrict__ Ctx) {      // [4096][2048] bf16
    const int S = 2048;
    int pair = blockIdx.x, h = blockIdx.y, b = blockIdx.z, g = h >> 3;
    int tid = threadIdx.x, lane = tid & 63, w = tid >> 6;
    int lg = lane >> 4, lr = lane & 15;
    size_t tok0 = (size_t)b * S;

    __shared__ unsigned short Kl[2][64 * 128];   // [kv][d] swizzled, 16KB each
    __shared__ unsigned short Vl[2][128 * 64];   // [d][kv] swizzled, 16KB each
    __shared__ unsigned short Pl[4][16][72];     // per-wave P^T [q=lr][kv]

    const float cexp = 0.08838834764831845f * 1.4426950408889634f; // 1/sqrt(128)*log2e

    // staging maps (inverse-swizzled global source -> linear LDS dest)
    int krow_l = w * 4 + (lane >> 4);                 // 0..15
    int kc16   = (lane & 15) ^ (krow_l & 7);
    int vrow_l = w * 8 + (lane >> 3);                 // 0..31
    int vc16   = (lane & 7) ^ (vrow_l & 7);
    const unsigned short* ksrcB = Kb + (tok0 + krow_l) * 256 + g * 128 + kc16 * 8;
    const unsigned short* vsrcB = Vt + (size_t)(g * 128 + vrow_l) * 4096 + b * S + vc16 * 8;
    int kswz = (lr & 7) << 3;

    auto stageKV = [&](int buf, int kvt) {
        const unsigned short* ks_ = ksrcB + (size_t)kvt * 64 * 256;
        unsigned short* kd = &Kl[buf][w * 512];
#pragma unroll
        for (int i = 0; i < 4; i++)
            load_lds16(ks_ + (size_t)i * 16 * 256, kd + i * 2048);
        const unsigned short* vs_ = vsrcB + kvt * 64;
        unsigned short* vd = &Vl[buf][w * 512];
#pragma unroll
        for (int i = 0; i < 4; i++)
            load_lds16(vs_ + (size_t)i * 32 * 4096, vd + i * 2048);
    };

    for (int hf = 0; hf < 2; hf++) {
        int qt = hf ? (31 - pair) : pair;
        int q0 = qt * 64 + w * 16;
        int myq = q0 + lr;                 // this lane's q row

        bf16x8 qf[4];
#pragma unroll
        for (int ks = 0; ks < 4; ks++)
            qf[ks] = *(const bf16x8*)(Qb + (tok0 + myq) * 2048 + h * 128 + ks * 32 + 8 * lg);

        f32x4 o[8];
#pragma unroll
        for (int t = 0; t < 8; t++) o[t] = f32x4{0.f, 0.f, 0.f, 0.f};
        float mX = -1e30f, lX = 0.f;

        int nkv = qt + 1;
        stageKV(0, 0);
        __syncthreads();

        for (int kvt = 0; kvt < nkv; kvt++) {
            int cur = kvt & 1;
            int kv0 = kvt * 64;
            if (kvt + 1 < nkv) stageKV(cur ^ 1, kvt + 1);   // prefetch next tile

            // ---- S^T = mfma(K_frag, Q_frag): lane holds S^T[kv=c*16+4*lg+r][q=lr]
            f32x4 sacc[4];
#pragma unroll
            for (int c = 0; c < 4; c++) sacc[c] = f32x4{0.f, 0.f, 0.f, 0.f};
#pragma unroll
            for (int c = 0; c < 4; c++) {
#pragma unroll
                for (int ks = 0; ks < 4; ks++) {
                    bf16x8 kf = *(const bf16x8*)&Kl[cur][(c * 16 + lr) * 128 + ((ks * 32 + 8 * lg) ^ kswz)];
                    sacc[c] = __builtin_amdgcn_mfma_f32_16x16x32_bf16(kf, qf[ks], sacc[c], 0, 0, 0);
                }
            }

            // ---- per-lane scalar online softmax over 16 values (+2 shfls for kv row)
            float pm = -1e30f;
            if (kvt == qt) {
#pragma unroll
                for (int c = 0; c < 4; c++)
#pragma unroll
                    for (int r = 0; r < 4; r++) {
                        float s = sacc[c][r] * cexp;
                        if (kv0 + c * 16 + 4 * lg + r > myq) s = -1e30f;
                        sacc[c][r] = s;
                        pm = fmaxf(pm, s);
                    }
            } else {
#pragma unroll
                for (int c = 0; c < 4; c++)
#pragma unroll
                    for (int r = 0; r < 4; r++) {
                        float s = sacc[c][r] * cexp;
                        sacc[c][r] = s;
                        pm = fmaxf(pm, s);
                    }
            }
            pm = fmaxf(pm, __shfl_xor(pm, 16));
            pm = fmaxf(pm, __shfl_xor(pm, 32));
            if (!__all(pm <= mX + 8.0f)) {        // T13 defer-max (P bounded by 2^8)
                float mn = fmaxf(mX, pm);
                float al = __builtin_exp2f(mX - mn);
                mX = mn;
                lX *= al;
#pragma unroll
                for (int t = 0; t < 8; t++)
#pragma unroll
                    for (int r = 0; r < 4; r++) o[t][r] *= al;
            }
            float ts = 0.f;
#pragma unroll
            for (int c = 0; c < 4; c++)
#pragma unroll
                for (int r = 0; r < 4; r++) {
                    float e = __builtin_exp2f(sacc[c][r] - mX);
                    sacc[c][r] = e;
                    ts += e;
                }
            ts += __shfl_xor(ts, 16);
            ts += __shfl_xor(ts, 32);
            lX += ts;

            // ---- P^T -> per-wave LDS, packed u32 (8 stores)
#pragma unroll
            for (int c = 0; c < 4; c++)
#pragma unroll
                for (int e = 0; e < 2; e++) {
                    unsigned u = (unsigned)f2bf(sacc[c][2 * e]) |
                                 ((unsigned)f2bf(sacc[c][2 * e + 1]) << 16);
                    *(unsigned*)&Pl[w][lr][c * 16 + 4 * lg + 2 * e] = u;
                }
            bf16x8 pf0 = *(const bf16x8*)&Pl[w][lr][8 * lg];
            bf16x8 pf1 = *(const bf16x8*)&Pl[w][lr][32 + 8 * lg];

            // ---- O^T += mfma(V_frag, P_frag): lane holds O^T[d=t*16+4*lg+r][q=lr]
#pragma unroll
            for (int t = 0; t < 8; t++) {
                bf16x8 vf0 = *(const bf16x8*)&Vl[cur][(t * 16 + lr) * 64 + ((8 * lg) ^ kswz)];
                bf16x8 vf1 = *(const bf16x8*)&Vl[cur][(t * 16 + lr) * 64 + ((32 + 8 * lg) ^ kswz)];
                o[t] = __builtin_amdgcn_mfma_f32_16x16x32_bf16(vf0, pf0, o[t], 0, 0, 0);
                o[t] = __builtin_amdgcn_mfma_f32_16x16x32_bf16(vf1, pf1, o[t], 0, 0, 0);
            }
            __syncthreads();   // next-tile staging complete; all waves done with cur
        }

        // ---- epilogue: lane writes its q row, 4 consecutive d per 8B store
        float inv = 1.0f / lX;
        unsigned short* crow = Ctx + (tok0 + myq) * 2048 + h * 128 + 4 * lg;
#pragma unroll
        for (int t = 0; t < 8; t++) {
            u16x4 pk{f2bf(o[t][0] * inv), f2bf(o[t][1] * inv),
                     f2bf(o[t][2] * inv), f2bf(o[t][3] * inv)};
            *(u16x4*)(crow + t * 16) = pk;
        }
    }
}

// ---------------- launch --------------------------------------------------------------
extern "C" void kernel_launch(void* const* d_in, const int* in_sizes, int n_in,
                              void* d_out, int out_size, void* d_ws, size_t ws_size,
                              hipStream_t stream) {
    const float* x  = (const float*)d_in[0];
    const float* Wq = (const float*)d_in[1];
    const float* bq = (const float*)d_in[2];
    const float* Wk = (const float*)d_in[3];
    const float* bk = (const float*)d_in[4];
    const float* Wv = (const float*)d_in[5];
    const float* bv = (const float*)d_in[6];
    const float* gq = (const float*)d_in[7];
    const float* gk = (const float*)d_in[8];
    const float* Wo = (const float*)d_in[9];
    const float* bo = (const float*)d_in[10];
    float* out = (float*)d_out;

    char* ws = (char*)d_ws;
    size_t off = 0;
    auto alloc = [&](size_t bytes) {
        void* p = ws + off;
        off += (bytes + 255) & ~(size_t)255;
        return p;
    };
    unsigned short* wqkvt = (unsigned short*)alloc((size_t)2560 * 2048 * 2);
    unsigned short* wot   = (unsigned short*)alloc((size_t)2048 * 2048 * 2);
    unsigned short* xb    = (unsigned short*)alloc((size_t)4096 * 2048 * 2);  // reused as ctx
    float*          C     = (float*)alloc((size_t)4096 * 2560 * 4);
    unsigned short* qb_   = (unsigned short*)alloc((size_t)4096 * 2048 * 2);
    unsigned short* kb_   = (unsigned short*)alloc((size_t)4096 * 256 * 2);
    unsigned short* vt    = (unsigned short*)alloc((size_t)512 * 4096 * 2);
    float*          biascat = (float*)alloc((size_t)2560 * 4);
    unsigned short* ctx = xb;   // xb dead after proj GEMM

    // x -> bf16
    cvt_bf16_k<<<4096, 256, 0, stream>>>(x, xb, 1048576);
    // weights -> K-major bf16 (QKV fused)
    transpose_cvt2<<<dim3(64, 64), 256, 0, stream>>>(Wq, wqkvt, 2048, 2048);
    transpose_cvt2<<<dim3(8, 64),  256, 0, stream>>>(Wk, wqkvt + (size_t)2048 * 2048, 256, 2048);
    transpose_cvt2<<<dim3(8, 64),  256, 0, stream>>>(Wv, wqkvt + (size_t)2304 * 2048, 256, 2048);
    transpose_cvt2<<<dim3(64, 64), 256, 0, stream>>>(Wo, wot, 2048, 2048);
    concat_bias<<<10, 256, 0, stream>>>(bq, bk, bv, biascat);

    // fused QKV projection -> C f32 [4096][2560]
    gemm_lds<<<dim3(20, 32), 256, 0, stream>>>(xb, wqkvt, biascat, C, 4096, 2560, 2048);

    // per-head RMSNorm + cvt
    rmsnorm_cvt2<<<16384, 256, 0, stream>>>(C, gq, qb_, 2560, 0,    4, 65536);
    rmsnorm_cvt2<<<2048,  256, 0, stream>>>(C, gk, kb_, 2560, 2048, 1, 8192);
    // V block -> V^T bf16 [512][4096]
    transpose_cvt2<<<dim3(16, 128), 256, 0, stream>>>(C + 2304, vt, 2560, 4096);

    // attention
    attn_kernel<<<dim3(16, 16, 2), 256, 0, stream>>>(qb_, kb_, vt, ctx);

    // output projection -> f32 out
    gemm_lds<<<dim3(16, 32), 256, 0, stream>>>(ctx, wot, bo, out, 4096, 2048, 2048);
}